// Round 3
// baseline (699.903 us; speedup 1.0000x reference)
//
#include <hip/hip_runtime.h>

#define S_LEN 2048
#define BATCH 16
#define DIM   512
#define KVB   32
#define NT    (S_LEN / KVB)   // 64 kv tiles

typedef __bf16 bf16x8 __attribute__((ext_vector_type(8)));
typedef float  f32x4  __attribute__((ext_vector_type(4)));
typedef float  f32x16 __attribute__((ext_vector_type(16)));
typedef unsigned int u32x4 __attribute__((ext_vector_type(4)));

static __device__ __forceinline__ unsigned short f2bf(float f) {
    __bf16 h = (__bf16)f;
    return __builtin_bit_cast(unsigned short, h);
}
static __device__ __forceinline__ bf16x8 ld_bf8(const unsigned short* p) {
    u32x4 v = *reinterpret_cast<const u32x4*>(p);
    return __builtin_bit_cast(bf16x8, v);
}
static __device__ __forceinline__ f32x4 mfma16(bf16x8 a, bf16x8 b, f32x4 c) {
    return __builtin_amdgcn_mfma_f32_16x16x32_bf16(a, b, c, 0, 0, 0);
}
static __device__ __forceinline__ f32x16 mfma32(bf16x8 a, bf16x8 b, f32x16 c) {
    return __builtin_amdgcn_mfma_f32_32x32x16_bf16(a, b, c, 0, 0, 0);
}
static __device__ __forceinline__ void gload16(const unsigned short* g, unsigned short* l) {
    __builtin_amdgcn_global_load_lds(
        (const __attribute__((address_space(1))) unsigned int*)g,
        (__attribute__((address_space(3))) unsigned int*)l, 16, 0, 0);
}
static __device__ __forceinline__ void waitv8() {
    asm volatile("s_waitcnt vmcnt(8)" ::: "memory");
    __builtin_amdgcn_sched_barrier(0);
}
static __device__ __forceinline__ void waitlg0() {
    asm volatile("s_waitcnt lgkmcnt(0)" ::: "memory");
    __builtin_amdgcn_sched_barrier(0);
}

// ---------------- pack Wv fp32 -> bf16 [512][512] ----------------
__global__ void pack_wv(const float* __restrict__ wv, unsigned short* __restrict__ out) {
    int i = blockIdx.x * blockDim.x + threadIdx.x;
    float4 v = reinterpret_cast<const float4*>(wv)[i];
    uint2 r;
    r.x = (unsigned)f2bf(v.x) | ((unsigned)f2bf(v.y) << 16);
    r.y = (unsigned)f2bf(v.z) | ((unsigned)f2bf(v.w) << 16);
    reinterpret_cast<uint2*>(out)[i] = r;
}

// ---------------- pack V^T: seq [S][B][D] f32 -> vt [B][D][S] bf16 ----------------
__global__ void pack_vt(const float* __restrict__ seq, unsigned short* __restrict__ vt) {
    __shared__ float tile[32][33];
    int b  = blockIdx.z;
    int d0 = blockIdx.y * 32;
    int s0 = blockIdx.x * 32;
    int t  = threadIdx.x;
    {
        int sl = t >> 3, c4 = (t & 7) * 4;
        float4 v = *reinterpret_cast<const float4*>(
            seq + (size_t)(s0 + sl) * (BATCH * DIM) + (size_t)b * DIM + d0 + c4);
        tile[sl][c4 + 0] = v.x; tile[sl][c4 + 1] = v.y;
        tile[sl][c4 + 2] = v.z; tile[sl][c4 + 3] = v.w;
    }
    __syncthreads();
    {
        int dl = t >> 3, s4 = (t & 7) * 4;
        uint2 r;
        r.x = (unsigned)f2bf(tile[s4 + 0][dl]) | ((unsigned)f2bf(tile[s4 + 1][dl]) << 16);
        r.y = (unsigned)f2bf(tile[s4 + 2][dl]) | ((unsigned)f2bf(tile[s4 + 3][dl]) << 16);
        *reinterpret_cast<uint2*>(
            vt + (size_t)b * DIM * S_LEN + (size_t)(d0 + dl) * S_LEN + s0 + s4) = r;
    }
}

// ---------------- value = tanh(seq_in @ Wv^T + bv) -> bf16 [B*S][512] ----------------
__global__ void __launch_bounds__(256) gemm_value(
        const float* __restrict__ seq, const unsigned short* __restrict__ wvb,
        const float* __restrict__ bv, unsigned short* __restrict__ val) {
    __shared__ unsigned short Asm[64][72];
    __shared__ unsigned short Bsm[64][72];
    int t  = threadIdx.x;
    int rb = blockIdx.x * 64;
    int cb = blockIdx.y * 64;
    int w = t >> 6, l = t & 63;
    int mi = w >> 1, ni = w & 1;
    int l15 = l & 15, lh = l >> 4;
    f32x4 acc[2][2] = {};

    int srow = t >> 2;
    int qc   = (t & 3) * 16;
    int gr = rb + srow;
    int sb = gr >> 11, ss = gr & 2047;
    const float* aSrc = seq + ((size_t)ss * BATCH + sb) * DIM + qc;
    const unsigned short* bSrc = wvb + (size_t)(cb + srow) * DIM + qc;

    for (int k0 = 0; k0 < DIM; k0 += 64) {
        unsigned short ar[16];
        #pragma unroll
        for (int j = 0; j < 4; ++j) {
            float4 v = *reinterpret_cast<const float4*>(aSrc + k0 + j * 4);
            ar[j * 4 + 0] = f2bf(v.x); ar[j * 4 + 1] = f2bf(v.y);
            ar[j * 4 + 2] = f2bf(v.z); ar[j * 4 + 3] = f2bf(v.w);
        }
        *reinterpret_cast<u32x4*>(&Asm[srow][qc])     = *reinterpret_cast<u32x4*>(&ar[0]);
        *reinterpret_cast<u32x4*>(&Asm[srow][qc + 8]) = *reinterpret_cast<u32x4*>(&ar[8]);
        u32x4 b0 = *reinterpret_cast<const u32x4*>(bSrc + k0);
        u32x4 b1 = *reinterpret_cast<const u32x4*>(bSrc + k0 + 8);
        *reinterpret_cast<u32x4*>(&Bsm[srow][qc])     = b0;
        *reinterpret_cast<u32x4*>(&Bsm[srow][qc + 8]) = b1;
        __syncthreads();
        #pragma unroll
        for (int kf = 0; kf < 2; ++kf) {
            bf16x8 af[2], bfm[2];
            #pragma unroll
            for (int i = 0; i < 2; ++i)
                af[i] = ld_bf8(&Asm[mi * 32 + i * 16 + l15][kf * 32 + lh * 8]);
            #pragma unroll
            for (int j = 0; j < 2; ++j)
                bfm[j] = ld_bf8(&Bsm[ni * 32 + j * 16 + l15][kf * 32 + lh * 8]);
            #pragma unroll
            for (int i = 0; i < 2; ++i)
                #pragma unroll
                for (int j = 0; j < 2; ++j)
                    acc[i][j] = mfma16(af[i], bfm[j], acc[i][j]);
        }
        __syncthreads();
    }
    #pragma unroll
    for (int i = 0; i < 2; ++i) {
        #pragma unroll
        for (int j = 0; j < 2; ++j) {
            int gcol = cb + ni * 32 + j * 16 + l15;
            float bias = bv[gcol];
            #pragma unroll
            for (int r = 0; r < 4; ++r) {
                int grow = rb + mi * 32 + i * 16 + lh * 4 + r;
                float x = acc[i][j][r] + bias;
                val[(size_t)grow * DIM + gcol] = f2bf(tanhf(x));
            }
        }
    }
}

// ---------------- fused flash attention v3 ----------------
// 512 thr = 8 waves. Waves 0-3: QK producers (qi=w&1, ksh=w>>1 K-half), one iter
// ahead, 32x32x16 MFMA, partial-S into LDS. Waves 4-7: softmax + PV consumers
// (qi=(w-4)&1, di=(w-4)>>1), O[32q][256d]=8 f32x16. K,V double-buffered via
// global_load_lds with counted vmcnt(8); 3 raw barriers/iter; defer-max rescale.
__global__ void __launch_bounds__(512) attn_fused(
        const unsigned short* __restrict__ val, const unsigned short* __restrict__ vt,
        float* __restrict__ out) {
    extern __shared__ char smem[];
    unsigned short* Kt = (unsigned short*)smem;               // [2][32][512]
    unsigned short* Vt = (unsigned short*)(smem + 65536);     // [2][256][64] pair-rows
    float*          Sp = (float*)(smem + 131072);             // [2][64][36] partial S
    unsigned short* Pb = (unsigned short*)(smem + 149504);    // [64][40]
    float* stm = (float*)(smem + 154624);
    float* stl = stm + 64;
    float* sts = stm + 128;

    const int t = threadIdx.x;
    const int w = t >> 6, l = t & 63;
    const int l31 = l & 31, lh1 = l >> 5;

    int wg  = blockIdx.x;
    int swz = (wg & 7) * 64 + (wg >> 3);     // XCD-chunked, bijective (512 = 8*64)
    int b   = swz >> 5;
    int qb  = (swz & 31) * 64;

    const unsigned short* valb = val + (size_t)b * S_LEN * DIM;
    const unsigned short* vtb  = vt  + (size_t)b * DIM * S_LEN;

    if (t < 64) { stm[t] = -3.0e38f; stl[t] = 0.0f; }

    // ======== QK-role state ========
    const int qi_k = w & 1, ksh = w >> 1;          // valid w<4
    bf16x8 qf[16];
    int koff[16];
    // ======== PV-role state ========
    const int pvw = w - 4;
    const int qi_p = pvw & 1, di = pvw >> 1;       // valid w>=4
    f32x16 o[8] = {};
    int voff[8][2];

    auto stageK = [&](int buf, int tile) {
        int kv0 = tile * KVB;
        #pragma unroll
        for (int i = 0; i < 8; ++i) {
            int row = i * 4 + w;                               // wave-uniform
            const unsigned short* src =
                valb + (size_t)(kv0 + row) * DIM + ((l ^ (row & 7)) * 8);
            unsigned short* dst = Kt + buf * 16384 + (i * 256 + w * 64) * 8;
            gload16(src, dst);
        }
    };
    auto stageV = [&](int buf, int tile) {
        int kv0 = tile * KVB;
        int p = t - 256;
        #pragma unroll
        for (int i = 0; i < 8; ++i) {
            int flat = i * 256 + p;
            int prow = flat >> 3;                              // per-lane
            int g = (flat & 7) ^ (prow & 7);                   // logical granule
            int d = prow * 2 + (g >> 2);
            const unsigned short* src =
                vtb + (size_t)d * S_LEN + kv0 + (g & 3) * 8;
            unsigned short* dst = Vt + buf * 16384 + (i * 256 + pvw * 64) * 8;
            gload16(src, dst);
        }
    };

    if (w < 4) {
        // Q fragments: rows qb + qi_k*32 + l31, K-half ksh*256 (64 VGPR)
        const unsigned short* qrow =
            valb + (size_t)(qb + qi_k * 32 + l31) * DIM + ksh * 256 + lh1 * 8;
        #pragma unroll
        for (int s = 0; s < 16; ++s) qf[s] = ld_bf8(qrow + s * 16);
        #pragma unroll
        for (int s = 0; s < 16; ++s) {
            int glog = ksh * 32 + s * 2 + lh1;
            koff[s] = l31 * 512 + ((glog ^ (l31 & 7)) * 8);
        }
        stageK(0, 0);
        stageK(1, 1);
    } else {
        #pragma unroll
        for (int td = 0; td < 8; ++td) {
            #pragma unroll
            for (int s2 = 0; s2 < 2; ++s2) {
                int d = di * 256 + td * 32 + l31;
                int prow = d >> 1;
                int glog = (d & 1) * 4 + s2 * 2 + lh1;
                voff[td][s2] = prow * 64 + ((glog ^ (prow & 7)) * 8);
            }
        }
        stageV(0, 0);
    }

    auto s_write = [&](const f32x16& acc) {
        #pragma unroll
        for (int rr = 0; rr < 16; ++rr) {
            int cr = (rr & 3) + 8 * (rr >> 2) + 4 * lh1;
            Sp[ksh * 2304 + (qi_k * 32 + cr) * 36 + l31] = acc[rr];
        }
    };

    // ---- prologue: compute S(0) ----
    waitv8();                       // QK: K(0) landed (K(1) in flight); PV: no-op
    __builtin_amdgcn_s_barrier();
    if (w < 4) {
        f32x16 acc0 = {};
        const unsigned short* kb = Kt;      // buf 0
        #pragma unroll
        for (int s = 0; s < 16; ++s) {
            bf16x8 kf = ld_bf8(kb + koff[s]);
            acc0 = mfma32(qf[s], kf, acc0);
        }
        s_write(acc0);
    }
    waitlg0();
    __builtin_amdgcn_s_barrier();

    // ---- main loop: iter kt computes QK(kt+1) and softmax+PV(kt) ----
    for (int kt = 0; kt < NT; ++kt) {
        if (w < 4) {
            int tile = (kt + 2 <= NT - 1) ? kt + 2 : NT - 1;
            stageK(kt & 1, tile);
        } else {
            int tile = (kt + 1 <= NT - 1) ? kt + 1 : NT - 1;
            stageV((kt + 1) & 1, tile);
        }
        waitv8();                                   // own prev staging batch done
        __builtin_amdgcn_s_barrier();               // beta: tiles ready

        f32x16 acc = {};
        if (w < 4) {
            if (kt < NT - 1) {
                const unsigned short* kb = Kt + ((kt + 1) & 1) * 16384;
                #pragma unroll
                for (int s = 0; s < 8; ++s) {
                    bf16x8 kf = ld_bf8(kb + koff[s]);
                    acc = mfma32(qf[s], kf, acc);
                }
            }
        } else {
            // ---- online softmax over S(kt), 64 rows x 4 lanes ----
            int p = t - 256;
            int row = p >> 2, c8 = (p & 3) * 8;
            const float* sp0 = Sp + row * 36 + c8;
            f32x4 x0 = *(const f32x4*)sp0 + *(const f32x4*)(sp0 + 2304);
            f32x4 x1 = *(const f32x4*)(sp0 + 4) + *(const f32x4*)(sp0 + 2308);
            float mt = fmaxf(fmaxf(fmaxf(x0[0], x0[1]), fmaxf(x0[2], x0[3])),
                             fmaxf(fmaxf(x1[0], x1[1]), fmaxf(x1[2], x1[3])));
            mt = fmaxf(mt, __shfl_xor(mt, 1, 64));
            mt = fmaxf(mt, __shfl_xor(mt, 2, 64));
            float m_old = stm[row];
            float m_new = (mt > m_old + 8.0f) ? mt : m_old;   // defer-max THR=8
            float e0 = __expf(x0[0] - m_new), e1 = __expf(x0[1] - m_new);
            float e2 = __expf(x0[2] - m_new), e3 = __expf(x0[3] - m_new);
            float e4 = __expf(x1[0] - m_new), e5 = __expf(x1[1] - m_new);
            float e6 = __expf(x1[2] - m_new), e7 = __expf(x1[3] - m_new);
            float lt = ((e0 + e1) + (e2 + e3)) + ((e4 + e5) + (e6 + e7));
            lt += __shfl_xor(lt, 1, 64);
            lt += __shfl_xor(lt, 2, 64);
            u32x4 pk;
            pk[0] = (unsigned)f2bf(e0) | ((unsigned)f2bf(e1) << 16);
            pk[1] = (unsigned)f2bf(e2) | ((unsigned)f2bf(e3) << 16);
            pk[2] = (unsigned)f2bf(e4) | ((unsigned)f2bf(e5) << 16);
            pk[3] = (unsigned)f2bf(e6) | ((unsigned)f2bf(e7) << 16);
            *(u32x4*)(Pb + row * 40 + c8) = pk;
            if ((p & 3) == 0) {
                float alpha = (m_new == m_old) ? 1.0f : __expf(m_old - m_new);
                stm[row] = m_new;
                stl[row] = stl[row] * alpha + lt;
                sts[row] = alpha;
            }
        }
        waitlg0();
        __builtin_amdgcn_s_barrier();               // gamma: P/stats ready, S free

        if (w < 4) {
            if (kt < NT - 1) {
                const unsigned short* kb = Kt + ((kt + 1) & 1) * 16384;
                #pragma unroll
                for (int s = 8; s < 16; ++s) {
                    bf16x8 kf = ld_bf8(kb + koff[s]);
                    acc = mfma32(qf[s], kf, acc);
                }
                s_write(acc);
            }
        } else {
            // ---- rescale O (deferred) + PV ----
            float al[16];
            bool need = false;
            #pragma unroll
            for (int rr = 0; rr < 16; ++rr) {
                int cr = (rr & 3) + 8 * (rr >> 2) + 4 * lh1;
                al[rr] = sts[qi_p * 32 + cr];
                need = need || (al[rr] != 1.0f);
            }
            if (__any((int)need)) {
                #pragma unroll
                for (int td = 0; td < 8; ++td)
                    #pragma unroll
                    for (int rr = 0; rr < 16; ++rr) o[td][rr] *= al[rr];
            }
            bf16x8 pa0 = ld_bf8(Pb + (qi_p * 32 + l31) * 40 + lh1 * 8);
            bf16x8 pa1 = ld_bf8(Pb + (qi_p * 32 + l31) * 40 + 16 + lh1 * 8);
            const unsigned short* vb = Vt + (kt & 1) * 16384;
            #pragma unroll
            for (int td = 0; td < 8; ++td) {
                bf16x8 v0 = ld_bf8(vb + voff[td][0]);
                o[td] = mfma32(pa0, v0, o[td]);
                bf16x8 v1 = ld_bf8(vb + voff[td][1]);
                o[td] = mfma32(pa1, v1, o[td]);
            }
        }
        waitlg0();
        __builtin_amdgcn_s_barrier();               // alpha: S(kt+1) ready
    }

    // ---- epilogue: PV waves write O/l ----
    if (w >= 4) {
        float li[16];
        #pragma unroll
        for (int rr = 0; rr < 16; ++rr) {
            int cr = (rr & 3) + 8 * (rr >> 2) + 4 * lh1;
            li[rr] = 1.0f / stl[qi_p * 32 + cr];
        }
        #pragma unroll
        for (int td = 0; td < 8; ++td) {
            int col = di * 256 + td * 32 + l31;
            #pragma unroll
            for (int rr = 0; rr < 16; ++rr) {
                int cr = (rr & 3) + 8 * (rr >> 2) + 4 * lh1;
                int row = qb + qi_p * 32 + cr;
                out[(size_t)row * (BATCH * DIM) + (size_t)b * DIM + col] =
                    o[td][rr] * li[rr];
            }
        }
    }
}

extern "C" void kernel_launch(void* const* d_in, const int* in_sizes, int n_in,
                              void* d_out, int out_size, void* d_ws, size_t ws_size,
                              hipStream_t stream) {
    const float* seq = (const float*)d_in[0];   // [S][B][D] f32
    const float* wv  = (const float*)d_in[1];   // [D][D] f32
    const float* bv  = (const float*)d_in[2];   // [D] f32
    float* outp = (float*)d_out;                // [S][B][D] f32

    unsigned short* wsVal = (unsigned short*)d_ws;                          // 32 MB
    unsigned short* wsVt  = (unsigned short*)((char*)d_ws + 33554432);      // 32 MB
    unsigned short* wsWv  = (unsigned short*)((char*)d_ws + 67108864);      // 0.5 MB

    pack_wv<<<dim3(DIM * DIM / 4 / 256), dim3(256), 0, stream>>>(wv, wsWv);
    pack_vt<<<dim3(S_LEN / 32, DIM / 32, BATCH), dim3(256), 0, stream>>>(seq, wsVt);
    gemm_value<<<dim3(BATCH * S_LEN / 64, DIM / 64), dim3(256), 0, stream>>>(
        seq, wsWv, bv, wsVal);
    attn_fused<<<dim3(512), dim3(512), 155392, stream>>>(wsVal, wsVt, outp);
}